// Round 5
// baseline (326.751 us; speedup 1.0000x reference)
//
#include <hip/hip_runtime.h>

// Problem constants: x:(B,T,2P) f32, resolution:(B,T,2) f32, origin:(B,T,2) f32
// -> out:(B,T,H,W,P) f32 one-hot raster grid.
#define BB 32
#define TT 10
#define PP 25
#define HH 100
#define WW 100

#define CELLS (HH * WW)                  // 10,000 cells per (b,t)
#define ELEMS_PER_BT (CELLS * PP)        // 250,000 floats per (b,t)
#define BLOCKS_PER_BT 10                 // chunks align exactly with bt ranges
#define F4_PER_BLOCK 6250                // 25,000 elems = 100 KB per block
#define CELLS_PER_BLOCK (CELLS / BLOCKS_PER_BT)  // 1000 cells per block

typedef float f32x4 __attribute__((ext_vector_type(4)));

// R4 lesson: fusing the one-hot compare into the store stream halves store BW
// (per-16B LDS reads + compares + p-wrap branch; nt bypasses L2 write-combine).
// This version makes the stream loop literally a memset (zeros only), then
// fixes up the <=25 one-cells per bt AFTER __syncthreads. gfx950 __syncthreads
// emits s_waitcnt vmcnt(0) before s_barrier, so every zero-store in this
// block's range is retired before any fixup store issues; fixup only targets
// this block's own range (chunking aligns with bt and cell boundaries).
__global__ __launch_bounds__(256) void raster_zero_fixup_kernel(
        const float* __restrict__ x,
        const float* __restrict__ resolution,
        const float* __restrict__ origin,
        float* __restrict__ out) {
    const int bid = blockIdx.x;            // 0..3199
    const int tid = threadIdx.x;
    const int bt  = bid / BLOCKS_PER_BT;   // 0..319
    const int seg = bid % BLOCKS_PER_BT;   // 0..9

    float* const chunk =
        out + (size_t)bt * ELEMS_PER_BT + (size_t)seg * (F4_PER_BLOCK * 4);

    // ---- Phase 1: pure memset-style zero of this block's 100 KB chunk.
    // Lanes contiguous: each wave stores 1 KiB per iteration, no compute.
    const f32x4 z = {0.0f, 0.0f, 0.0f, 0.0f};
#pragma unroll 4
    for (int i = tid; i < F4_PER_BLOCK; i += 256) {
        reinterpret_cast<f32x4*>(chunk)[i] = z;
    }

    __syncthreads();  // vmcnt(0) drain: zeros complete before fixup stores

    // ---- Phase 2: fixup the one-cells that land in this block's cell range.
    if (tid < PP) {
        const float px = x[bt * (2 * PP) + 2 * tid];      // x-coord
        const float py = x[bt * (2 * PP) + 2 * tid + 1];  // y-coord
        const float r0 = resolution[bt * 2 + 0];          // row uses res[...,0]
        const float r1 = resolution[bt * 2 + 1];          // col uses res[...,1]
        const float o0 = origin[bt * 2 + 0];
        const float o1 = origin[bt * 2 + 1];
        // jnp .astype(int32) truncates toward zero, same as C cast.
        const int row = (int)(py / r0 + o0);
        const int col = (int)(px / r1 + o1);
        if (row >= 0 && row < HH && col >= 0 && col < WW) {
            const int cellIdx = row * WW + col;
            const int lo = seg * CELLS_PER_BLOCK;
            if (cellIdx >= lo && cellIdx < lo + CELLS_PER_BLOCK) {
                out[(size_t)bt * ELEMS_PER_BT + (size_t)cellIdx * PP + tid] = 1.0f;
            }
        }
    }
}

extern "C" void kernel_launch(void* const* d_in, const int* in_sizes, int n_in,
                              void* d_out, int out_size, void* d_ws, size_t ws_size,
                              hipStream_t stream) {
    const float* x          = (const float*)d_in[0];
    const float* resolution = (const float*)d_in[1];
    const float* origin     = (const float*)d_in[2];
    float* out = (float*)d_out;

    // Single dispatch: every logical output element written exactly once
    // (zeros), then <=25/bt overwritten with 1.0 in-block after the barrier.
    const int nblocks = BB * TT * BLOCKS_PER_BT;   // 3200 blocks, 12.5/CU
    raster_zero_fixup_kernel<<<nblocks, 256, 0, stream>>>(x, resolution, origin,
                                                          out);
}